// Round 9
// baseline (266.010 us; speedup 1.0000x reference)
//
#include <hip/hip_runtime.h>

#define NB 1024
#define NN 128
#define KK 32
#define DM 64

constexpr float Y0 = 0.28209479177387814f;
constexpr float Y1 = 0.4886025119029199f;

typedef float f2 __attribute__((ext_vector_type(2)));
typedef unsigned long long ull;

// ws layout:
//   feats: [NB*NN][8] float  (px,py,pz,vx,vy,vz,|v|,mass)   4 MB
//   com:   [NB][4]   float                                   16 KB
//   nbr:   [NB*NN][32] uint8                                  4 MB

__global__ __launch_bounds__(128) void k1_prep(const float* __restrict__ in,
        float* __restrict__ feats, float* __restrict__ com, float* __restrict__ out)
{
    const int b = blockIdx.x, t = threadIdx.x;
    const float* p = in + ((size_t)b*NN + t)*7;
    const float m  = p[0];
    const float lx = p[1], ly = p[2], lz = p[3];
    const float vx = p[4], vy = p[5], vz = p[6];
    float w=m, wx=m*lx, wy=m*ly, wz=m*lz;
    #pragma unroll
    for (int s=1; s<64; s<<=1) {
        w  += __shfl_xor(w,  s);
        wx += __shfl_xor(wx, s);
        wy += __shfl_xor(wy, s);
        wz += __shfl_xor(wz, s);
    }
    __shared__ float red[2][4];
    if ((t & 63) == 0) { int wi=t>>6; red[wi][0]=w; red[wi][1]=wx; red[wi][2]=wy; red[wi][3]=wz; }
    __syncthreads();
    const float Wt = red[0][0]+red[1][0];
    const float cx = (red[0][1]+red[1][1])/Wt;
    const float cy = (red[0][2]+red[1][2])/Wt;
    const float cz = (red[0][3]+red[1][3])/Wt;
    const float px = lx-cx, py = ly-cy, pz = lz-cz;
    const float va = sqrtf(vx*vx+vy*vy+vz*vz);
    float4* f4 = (float4*)(feats + ((size_t)b*NN + t)*8);
    f4[0] = make_float4(px,py,pz,vx);
    f4[1] = make_float4(vy,vz,va,m);
    if (t==0) { float4* c4=(float4*)(com + (size_t)b*4); *c4 = make_float4(cx,cy,cz,0.f); }
    if (b < 8) out[(size_t)NB*NN*3 + (size_t)b*128 + t] = 0.f;   // zeros(B)
}

__device__ __forceinline__ ull sx64(ull v, int m) {
    return ((ull)(unsigned)__shfl_xor((int)(v>>32), m) << 32)
         |       (unsigned)__shfl_xor((int)(v & 0xffffffffu), m);
}

__device__ __forceinline__ void ce(ull& k, int lane, int stride, bool asc) {
    const ull p = sx64(k, stride);
    const bool lower   = (lane & stride) == 0;
    const bool keepmin = (lower == asc);
    const bool less    = (k < p);            // keys unique (index in low bits)
    const bool take_p  = keepmin ? !less : less;
    k = take_p ? p : k;
}

// wave-per-node exact top-32 via full bitonic sort of 128 u64 keys.
// grid = NB*4 blocks; block = quarter batch: 4 waves x 8 nodes sequential.
__global__ __launch_bounds__(256) void k2_knn(const float* __restrict__ feats,
                                              unsigned char* __restrict__ nbr)
{
    const int b = blockIdx.x >> 2, qtr = blockIdx.x & 3;
    const int t = threadIdx.x;
    const int lane = t & 63, w = t >> 6;
    __shared__ float4 sP[128];
    if (t < 128) sP[t] = *(const float4*)(feats + ((size_t)b*NN + t)*8);
    __syncthreads();
    const float4 A = sP[lane];
    const float4 B = sP[lane+64];
    const float INF = __int_as_float(0x7f800000);

    #pragma unroll 1
    for (int i=0; i<8; ++i) {
        const int n = qtr*32 + w*8 + i;
        const float4 C = sP[n];
        float dx=A.x-C.x, dy=A.y-C.y, dz=A.z-C.z;
        float d2a = dx*dx+dy*dy+dz*dz;
        dx=B.x-C.x; dy=B.y-C.y; dz=B.z-C.z;
        float d2b = dx*dx+dy*dy+dz*dz;
        if (lane    == n) d2a = INF;
        if (lane+64 == n) d2b = INF;
        // element e0 = lane (slot0), e1 = lane+64 (slot1)
        ull k0 = ((ull)__float_as_uint(d2a) << 32) | (unsigned)lane;
        ull k1 = ((ull)__float_as_uint(d2b) << 32) | (unsigned)(lane+64);

        // bitonic sort, sizes 2..64 (all strides cross-lane, <=32)
        #pragma unroll
        for (int size = 2; size <= 64; size <<= 1) {
            #pragma unroll
            for (int stride = size >> 1; stride >= 1; stride >>= 1) {
                const bool asc0 = (lane & size) == 0;     // size==64 -> always true
                const bool asc1 = (size == 64) ? false : asc0;
                ce(k0, lane, stride, asc0);
                ce(k1, lane, stride, asc1);
            }
        }
        // final merge size=128: stride 64 is the local pair, rest cross-lane, all ascending
        if (k0 > k1) { const ull tmp = k0; k0 = k1; k1 = tmp; }
        #pragma unroll
        for (int stride = 32; stride >= 1; stride >>= 1) {
            ce(k0, lane, stride, true);
            ce(k1, lane, stride, true);
        }
        // ranks 0..31 = slot0, lanes 0..31
        if (lane < 32)
            nbr[((size_t)b*NN + n)*32 + lane] = (unsigned char)(k0 & 0xffu);
    }
}

__global__ __launch_bounds__(256) void k3_main(const float* __restrict__ feats,
        const unsigned char* __restrict__ nbr, const float* __restrict__ Wm,
        const float* __restrict__ Wo, const float* __restrict__ com,
        float* __restrict__ out)
{
    const int b = blockIdx.x, t = threadIdx.x;
    __shared__ float4 sPos[128];                     // {px,py,pz,mass}
    __shared__ float4 sVel[128];                     // {vx,vy,vz,|v|}
    __shared__ __align__(16) float sXs[128*64];      // quad-XOR swizzled
    __shared__ float  sWm[20][64];
    __shared__ float  sWo[75][3];
    __shared__ float4 sE4[32][33];                   // {Y1*ux,Y1*uy,Y1*uz,dist}, padded
    __shared__ float  sPm[32][33];                   // prod_mass, padded
    __shared__ int    sSrc[32][33];                  // src node id, padded
    __shared__ float4 sSu[32];                       // per-node sum of Y1*u

    for (int i=t;i<1280;i+=256) ((float*)sWm)[i] = Wm[i];
    for (int i=t;i<225; i+=256) ((float*)sWo)[i] = Wo[i];
    if (t < 128) {
        const float4* f4 = (const float4*)(feats + ((size_t)b*NN + t)*8);
        sPos[t] = f4[0];   // px,py,pz,vx  -> repacked below
        sVel[t] = f4[1];   // vy,vz,va,m
    }
    __syncthreads();
    if (t < 128) {
        const float4 a = sPos[t], c = sVel[t];
        sPos[t] = make_float4(a.x,a.y,a.z,c.w);
        sVel[t] = make_float4(a.w,c.x,c.y,c.z);
    }
    __syncthreads();

    // Xs[n][d] = x[n](7) . Wm[0:7,d], swizzled store
    for (int i=t;i<8192;i+=256) {
        const int n = i>>6, d = i&63;
        const float4 P = sPos[n], V = sVel[n];
        float s = P.x*sWm[0][d];
        s = fmaf(P.y, sWm[1][d], s);
        s = fmaf(P.z, sWm[2][d], s);
        s = fmaf(V.x, sWm[3][d], s);
        s = fmaf(V.y, sWm[4][d], s);
        s = fmaf(V.z, sWm[5][d], s);
        s = fmaf(V.w, sWm[6][d], s);
        const int q = d>>2;
        sXs[(n<<6) + ((q ^ (n&7))<<2) + (d&3)] = s;
    }
    __syncthreads();

    const int dsub = t & 7, ng = t >> 3, d0 = dsub*8, q0 = dsub*2;
    f2 wc2[5][4];
    #pragma unroll
    for (int r=0;r<5;r++)
        #pragma unroll
        for (int j=0;j<4;j++) {
            wc2[r][j].x = sWm[15+r][d0+2*j];
            wc2[r][j].y = sWm[15+r][d0+2*j+1];
        }
    const float cmx = com[(size_t)b*4+0], cmy = com[(size_t)b*4+1], cmz = com[(size_t)b*4+2];

    #pragma unroll 1
    for (int ch=0; ch<4; ++ch) {
        // ---- edge-table build: 1024 edges, each computed once ----
        {
            const int nl = t>>3, j0 = (t&7)*4;
            const int n  = ch*32 + nl;
            const float4 Pn = sPos[n];
            const uchar4 nb4 = *(const uchar4*)(nbr + ((size_t)b*NN + n)*32 + j0);
            const int js[4] = {nb4.x, nb4.y, nb4.z, nb4.w};
            float sx=0.f, sy=0.f, sz=0.f;
            #pragma unroll
            for (int r=0;r<4;r++) {
                const int s = js[r];
                const float4 Ps = sPos[s];
                const float rx=Ps.x-Pn.x, ry=Ps.y-Pn.y, rz=Ps.z-Pn.z;
                const float dist = sqrtf(rx*rx+ry*ry+rz*rz);
                const float inv  = Y1 * __builtin_amdgcn_rcpf(fmaxf(dist,1e-12f));
                const float ux=rx*inv, uy=ry*inv, uz=rz*inv;
                sx+=ux; sy+=uy; sz+=uz;
                sE4[nl][j0+r] = make_float4(ux,uy,uz,dist);
                sPm[nl][j0+r] = Ps.w*Pn.w;
                sSrc[nl][j0+r] = s;
            }
            #pragma unroll
            for (int s=1;s<8;s<<=1) { sx+=__shfl_xor(sx,s); sy+=__shfl_xor(sy,s); sz+=__shfl_xor(sz,s); }
            if ((t&7)==0) sSu[nl] = make_float4(sx,sy,sz,0.f);
        }
        __syncthreads();

        // ---- main: per-node message accumulation over 32 edges (packed fp32) ----
        {
            const int n = ch*32 + ng;
            const float4 Pn = sPos[n], Vn = sVel[n];
            f2 xdb2[4];
            #pragma unroll
            for (int j=0;j<4;j++) {
                #pragma unroll
                for (int h=0;h<2;h++) {
                    const int c = 2*j+h;
                    float s = Y0 * sWm[14][d0+c];
                    s = fmaf(Pn.x, sWm[7][d0+c], s);
                    s = fmaf(Pn.y, sWm[8][d0+c], s);
                    s = fmaf(Pn.z, sWm[9][d0+c], s);
                    s = fmaf(Vn.x, sWm[10][d0+c], s);
                    s = fmaf(Vn.y, sWm[11][d0+c], s);
                    s = fmaf(Vn.z, sWm[12][d0+c], s);
                    s = fmaf(Vn.w, sWm[13][d0+c], s);
                    if (h==0) xdb2[j].x = s; else xdb2[j].y = s;
                }
            }
            f2 acc2[4];
            #pragma unroll
            for (int j=0;j<4;j++) acc2[j] = (f2){0.f,0.f};
            const f2 zero2 = (f2){0.f,0.f};
            #pragma unroll 8
            for (int e=0;e<32;e++) {
                const float4 E = sE4[ng][e];
                const float pm = sPm[ng][e];
                const int s = sSrc[ng][e];
                const int a0 = (s<<8) + ((q0 ^ (s&7))<<4);
                const float4 xsA = *(const float4*)((const char*)sXs + a0);
                const float4 xsB = *(const float4*)((const char*)sXs + (a0^16));
                f2 xs2[4];
                xs2[0] = (f2){xsA.x, xsA.y};
                xs2[1] = (f2){xsA.z, xsA.w};
                xs2[2] = (f2){xsB.x, xsB.y};
                xs2[3] = (f2){xsB.z, xsB.w};
                const f2 ex = (f2){E.x, E.x};
                const f2 ey = (f2){E.y, E.y};
                const f2 ez = (f2){E.z, E.z};
                const f2 ew = (f2){E.w, E.w};
                const f2 pm2 = (f2){pm, pm};
                #pragma unroll
                for (int j=0;j<4;j++) {
                    f2 v = xdb2[j] + xs2[j];
                    v = __builtin_elementwise_fma(ex,  wc2[0][j], v);
                    v = __builtin_elementwise_fma(ey,  wc2[1][j], v);
                    v = __builtin_elementwise_fma(ez,  wc2[2][j], v);
                    v = __builtin_elementwise_fma(ew,  wc2[3][j], v);
                    v = __builtin_elementwise_fma(pm2, wc2[4][j], v);
                    v = __builtin_elementwise_max(v, zero2);
                    acc2[j] += v;
                }
            }
            float p0=0.f,p1=0.f,p2=0.f;
            #pragma unroll
            for (int j=0;j<4;j++) {
                const float a0v = acc2[j].x*(1.0f/32.0f);
                const float a1v = acc2[j].y*(1.0f/32.0f);
                const int c0 = 2*j, c1 = 2*j+1;
                p0 = fmaf(a0v, sWo[11+d0+c0][0], p0);
                p1 = fmaf(a0v, sWo[11+d0+c0][1], p1);
                p2 = fmaf(a0v, sWo[11+d0+c0][2], p2);
                p0 = fmaf(a1v, sWo[11+d0+c1][0], p0);
                p1 = fmaf(a1v, sWo[11+d0+c1][1], p1);
                p2 = fmaf(a1v, sWo[11+d0+c1][2], p2);
            }
            #pragma unroll
            for (int s=1;s<8;s<<=1) {
                p0 += __shfl_xor(p0,s); p1 += __shfl_xor(p1,s); p2 += __shfl_xor(p2,s);
            }
            if (dsub == 0) {
                const float4 Su = sSu[ng];
                const float vinv = Y1 * __builtin_amdgcn_rcpf(fmaxf(Vn.w,1e-12f));
                const float na0 = 2.f*Y0;
                const float na1 = Su.x*(1.f/32.f) + Vn.x*vinv;
                const float na2 = Su.y*(1.f/32.f) + Vn.y*vinv;
                const float na3 = Su.z*(1.f/32.f) + Vn.z*vinv;
                const float xf[7] = {Pn.x,Pn.y,Pn.z,Vn.x,Vn.y,Vn.z,Vn.w};
                #pragma unroll
                for (int k=0;k<7;k++) {
                    p0 = fmaf(xf[k], sWo[k][0], p0);
                    p1 = fmaf(xf[k], sWo[k][1], p1);
                    p2 = fmaf(xf[k], sWo[k][2], p2);
                }
                p0 += na0*sWo[7][0] + na1*sWo[8][0] + na2*sWo[9][0] + na3*sWo[10][0];
                p1 += na0*sWo[7][1] + na1*sWo[8][1] + na2*sWo[9][1] + na3*sWo[10][1];
                p2 += na0*sWo[7][2] + na1*sWo[8][2] + na2*sWo[9][2] + na3*sWo[10][2];
                float* op = out + ((size_t)b*NN + n)*3;
                op[0] = Pn.x + cmx + p0;
                op[1] = Pn.y + cmy + p1;
                op[2] = Pn.z + cmz + p2;
            }
        }
        __syncthreads();   // full separation: next build's writes vs this main's reads
    }
}

extern "C" void kernel_launch(void* const* d_in, const int* in_sizes, int n_in,
                              void* d_out, int out_size, void* d_ws, size_t ws_size,
                              hipStream_t stream)
{
    const float* in = (const float*)d_in[0];
    const float* Wm = (const float*)d_in[1];
    const float* Wo = (const float*)d_in[2];
    float* out = (float*)d_out;
    float* feats = (float*)d_ws;                               // NB*NN*8 floats
    float* com   = feats + (size_t)NB*NN*8;                    // NB*4 floats
    unsigned char* nbr = (unsigned char*)(com + (size_t)NB*4); // NB*NN*32 u8

    k1_prep<<<NB,   128, 0, stream>>>(in, feats, com, out);
    k2_knn <<<NB*4, 256, 0, stream>>>(feats, nbr);
    k3_main<<<NB,   256, 0, stream>>>(feats, nbr, Wm, Wo, com, out);
}

// Round 10
// 178.960 us; speedup vs baseline: 1.4864x; 1.4864x over previous
//
#include <hip/hip_runtime.h>

#define NB 1024
#define NN 128
#define KK 32
#define DM 64

constexpr float Y0 = 0.28209479177387814f;
constexpr float Y1 = 0.4886025119029199f;

typedef float f2 __attribute__((ext_vector_type(2)));
typedef unsigned long long ull;

// ws layout:
//   feats: [NB*NN][8] float  (px,py,pz,vx,vy,vz,|v|,mass)   4 MB
//   com:   [NB][4]   float                                   16 KB
//   nbr:   [NB*NN][32] uint8                                  4 MB

__device__ __forceinline__ void ce_asc(ull& a, ull& b) {   // after: a<=b
    const bool lt = a < b;
    const ull lo = lt ? a : b, hi = lt ? b : a;
    a = lo; b = hi;
}
__device__ __forceinline__ void ce_desc(ull& a, ull& b) {  // after: a>=b
    const bool lt = a < b;
    const ull lo = lt ? a : b, hi = lt ? b : a;
    a = hi; b = lo;
}

template<bool ASC>
__device__ __forceinline__ void sort32(ull K[32]) {
    #pragma unroll
    for (int k = 2; k <= 32; k <<= 1)
        #pragma unroll
        for (int j = k >> 1; j > 0; j >>= 1)
            #pragma unroll
            for (int i = 0; i < 32; i++) {
                const int l = i ^ j;
                if (l > i) {
                    if ((((i & k) == 0) == ASC)) ce_asc(K[i], K[l]);
                    else                         ce_desc(K[i], K[l]);
                }
            }
}

__device__ __forceinline__ void clean32_asc(ull K[32]) {   // sort a bitonic seq
    #pragma unroll
    for (int j = 16; j > 0; j >>= 1)
        #pragma unroll
        for (int i = 0; i < 32; i++) {
            const int l = i ^ j;
            if (l > i) ce_asc(K[i], K[l]);
        }
}

// fused: com + centered features (k1, proven) + per-thread register-network top-32
__global__ __launch_bounds__(128) void k12_sel(const float* __restrict__ in,
        float* __restrict__ feats, float* __restrict__ com,
        unsigned char* __restrict__ nbr, float* __restrict__ out)
{
    const int b = blockIdx.x, t = threadIdx.x;
    __shared__ float4 sP[128];
    __shared__ float red[2][4];

    // ---- phase 1: proven k1 body ----
    const float* p = in + ((size_t)b*NN + t)*7;
    const float m  = p[0];
    const float lx = p[1], ly = p[2], lz = p[3];
    const float vx = p[4], vy = p[5], vz = p[6];
    float w=m, wx=m*lx, wy=m*ly, wz=m*lz;
    #pragma unroll
    for (int s=1; s<64; s<<=1) {
        w  += __shfl_xor(w,  s);
        wx += __shfl_xor(wx, s);
        wy += __shfl_xor(wy, s);
        wz += __shfl_xor(wz, s);
    }
    if ((t & 63) == 0) { int wi=t>>6; red[wi][0]=w; red[wi][1]=wx; red[wi][2]=wy; red[wi][3]=wz; }
    __syncthreads();
    const float Wt = red[0][0]+red[1][0];
    const float cx = (red[0][1]+red[1][1])/Wt;
    const float cy = (red[0][2]+red[1][2])/Wt;
    const float cz = (red[0][3]+red[1][3])/Wt;
    const float px = lx-cx, py = ly-cy, pz = lz-cz;
    const float va = sqrtf(vx*vx+vy*vy+vz*vz);
    float4* f4 = (float4*)(feats + ((size_t)b*NN + t)*8);
    f4[0] = make_float4(px,py,pz,vx);
    f4[1] = make_float4(vy,vz,va,m);
    if (t==0) { float4* c4=(float4*)(com + (size_t)b*4); *c4 = make_float4(cx,cy,cz,0.f); }
    if (b < 8) out[(size_t)NB*NN*3 + (size_t)b*128 + t] = 0.f;   // zeros(B)
    sP[t] = make_float4(px,py,pz,0.f);
    __syncthreads();

    // ---- phase 2: per-thread exact top-32 via register bitonic networks ----
    const float4 me = sP[t];
    const unsigned diag = 0x7f800000u;   // +inf bits for j == t
    ull S[32], C[32];
    #pragma unroll
    for (int i=0;i<32;i++) {
        const float4 o = sP[i];
        const float dx=o.x-me.x, dy=o.y-me.y, dz=o.z-me.z;
        const float d2 = dx*dx + dy*dy + dz*dz;
        const unsigned bits = (i==t) ? diag : __float_as_uint(d2);
        S[i] = ((ull)bits<<32) | (unsigned)i;
    }
    sort32<true>(S);
    #pragma unroll 1
    for (int c=1;c<4;c++) {
        #pragma unroll
        for (int i=0;i<32;i++) {
            const int j = c*32 + i;
            const float4 o = sP[j];
            const float dx=o.x-me.x, dy=o.y-me.y, dz=o.z-me.z;
            const float d2 = dx*dx + dy*dy + dz*dz;
            const unsigned bits = (j==t) ? diag : __float_as_uint(d2);
            C[i] = ((ull)bits<<32) | (unsigned)j;
        }
        sort32<false>(C);                     // C descending
        #pragma unroll
        for (int i=0;i<32;i++) S[i] = (S[i] < C[i]) ? S[i] : C[i];   // half-cleaner
        clean32_asc(S);                       // S = smallest 32, sorted
    }
    unsigned char* row = nbr + ((size_t)b*NN + t)*32;
    #pragma unroll
    for (int i=0;i<32;i+=4) {
        const unsigned wv = (unsigned)(S[i]   & 0xffu)
                          | ((unsigned)(S[i+1] & 0xffu) << 8)
                          | ((unsigned)(S[i+2] & 0xffu) << 16)
                          | ((unsigned)(S[i+3] & 0xffu) << 24);
        *(unsigned*)(row + i) = wv;
    }
}

__global__ __launch_bounds__(256) void k3_main(const float* __restrict__ feats,
        const unsigned char* __restrict__ nbr, const float* __restrict__ Wm,
        const float* __restrict__ Wo, const float* __restrict__ com,
        float* __restrict__ out)
{
    const int b = blockIdx.x, t = threadIdx.x;
    __shared__ float4 sPos[128];                     // {px,py,pz,mass}
    __shared__ float4 sVel[128];                     // {vx,vy,vz,|v|}
    __shared__ __align__(16) float sXs[128*64];      // quad-XOR swizzled
    __shared__ float  sWm[20][64];
    __shared__ float  sWo[75][3];
    __shared__ float4 sE4[32][33];                   // {Y1*ux,Y1*uy,Y1*uz,dist}, padded
    __shared__ float  sPm[32][33];                   // prod_mass, padded
    __shared__ int    sSrc[32][33];                  // src node id, padded
    __shared__ float4 sSu[32];                       // per-node sum of Y1*u

    for (int i=t;i<1280;i+=256) ((float*)sWm)[i] = Wm[i];
    for (int i=t;i<225; i+=256) ((float*)sWo)[i] = Wo[i];
    if (t < 128) {
        const float4* f4 = (const float4*)(feats + ((size_t)b*NN + t)*8);
        sPos[t] = f4[0];   // px,py,pz,vx  -> repacked below
        sVel[t] = f4[1];   // vy,vz,va,m
    }
    __syncthreads();
    if (t < 128) {
        const float4 a = sPos[t], c = sVel[t];
        sPos[t] = make_float4(a.x,a.y,a.z,c.w);
        sVel[t] = make_float4(a.w,c.x,c.y,c.z);
    }
    __syncthreads();

    // Xs[n][d] = x[n](7) . Wm[0:7,d], swizzled store
    for (int i=t;i<8192;i+=256) {
        const int n = i>>6, d = i&63;
        const float4 P = sPos[n], V = sVel[n];
        float s = P.x*sWm[0][d];
        s = fmaf(P.y, sWm[1][d], s);
        s = fmaf(P.z, sWm[2][d], s);
        s = fmaf(V.x, sWm[3][d], s);
        s = fmaf(V.y, sWm[4][d], s);
        s = fmaf(V.z, sWm[5][d], s);
        s = fmaf(V.w, sWm[6][d], s);
        const int q = d>>2;
        sXs[(n<<6) + ((q ^ (n&7))<<2) + (d&3)] = s;
    }
    __syncthreads();

    const int dsub = t & 7, ng = t >> 3, d0 = dsub*8, q0 = dsub*2;
    f2 wc2[5][4];
    #pragma unroll
    for (int r=0;r<5;r++)
        #pragma unroll
        for (int j=0;j<4;j++) {
            wc2[r][j].x = sWm[15+r][d0+2*j];
            wc2[r][j].y = sWm[15+r][d0+2*j+1];
        }
    const float cmx = com[(size_t)b*4+0], cmy = com[(size_t)b*4+1], cmz = com[(size_t)b*4+2];

    #pragma unroll 1
    for (int ch=0; ch<4; ++ch) {
        // ---- edge-table build: 1024 edges, each computed once ----
        {
            const int nl = t>>3, j0 = (t&7)*4;
            const int n  = ch*32 + nl;
            const float4 Pn = sPos[n];
            const uchar4 nb4 = *(const uchar4*)(nbr + ((size_t)b*NN + n)*32 + j0);
            const int js[4] = {nb4.x, nb4.y, nb4.z, nb4.w};
            float sx=0.f, sy=0.f, sz=0.f;
            #pragma unroll
            for (int r=0;r<4;r++) {
                const int s = js[r];
                const float4 Ps = sPos[s];
                const float rx=Ps.x-Pn.x, ry=Ps.y-Pn.y, rz=Ps.z-Pn.z;
                const float dist = sqrtf(rx*rx+ry*ry+rz*rz);
                const float inv  = Y1 * __builtin_amdgcn_rcpf(fmaxf(dist,1e-12f));
                const float ux=rx*inv, uy=ry*inv, uz=rz*inv;
                sx+=ux; sy+=uy; sz+=uz;
                sE4[nl][j0+r] = make_float4(ux,uy,uz,dist);
                sPm[nl][j0+r] = Ps.w*Pn.w;
                sSrc[nl][j0+r] = s;
            }
            #pragma unroll
            for (int s=1;s<8;s<<=1) { sx+=__shfl_xor(sx,s); sy+=__shfl_xor(sy,s); sz+=__shfl_xor(sz,s); }
            if ((t&7)==0) sSu[nl] = make_float4(sx,sy,sz,0.f);
        }
        __syncthreads();

        // ---- main: per-node message accumulation over 32 edges (packed fp32) ----
        {
            const int n = ch*32 + ng;
            const float4 Pn = sPos[n], Vn = sVel[n];
            f2 xdb2[4];
            #pragma unroll
            for (int j=0;j<4;j++) {
                #pragma unroll
                for (int h=0;h<2;h++) {
                    const int c = 2*j+h;
                    float s = Y0 * sWm[14][d0+c];
                    s = fmaf(Pn.x, sWm[7][d0+c], s);
                    s = fmaf(Pn.y, sWm[8][d0+c], s);
                    s = fmaf(Pn.z, sWm[9][d0+c], s);
                    s = fmaf(Vn.x, sWm[10][d0+c], s);
                    s = fmaf(Vn.y, sWm[11][d0+c], s);
                    s = fmaf(Vn.z, sWm[12][d0+c], s);
                    s = fmaf(Vn.w, sWm[13][d0+c], s);
                    if (h==0) xdb2[j].x = s; else xdb2[j].y = s;
                }
            }
            f2 acc2[4];
            #pragma unroll
            for (int j=0;j<4;j++) acc2[j] = (f2){0.f,0.f};
            const f2 zero2 = (f2){0.f,0.f};
            #pragma unroll 8
            for (int e=0;e<32;e++) {
                const float4 E = sE4[ng][e];
                const float pm = sPm[ng][e];
                const int s = sSrc[ng][e];
                const int a0 = (s<<8) + ((q0 ^ (s&7))<<4);
                const float4 xsA = *(const float4*)((const char*)sXs + a0);
                const float4 xsB = *(const float4*)((const char*)sXs + (a0^16));
                f2 xs2[4];
                xs2[0] = (f2){xsA.x, xsA.y};
                xs2[1] = (f2){xsA.z, xsA.w};
                xs2[2] = (f2){xsB.x, xsB.y};
                xs2[3] = (f2){xsB.z, xsB.w};
                const f2 ex = (f2){E.x, E.x};
                const f2 ey = (f2){E.y, E.y};
                const f2 ez = (f2){E.z, E.z};
                const f2 ew = (f2){E.w, E.w};
                const f2 pm2 = (f2){pm, pm};
                #pragma unroll
                for (int j=0;j<4;j++) {
                    f2 v = xdb2[j] + xs2[j];
                    v = __builtin_elementwise_fma(ex,  wc2[0][j], v);
                    v = __builtin_elementwise_fma(ey,  wc2[1][j], v);
                    v = __builtin_elementwise_fma(ez,  wc2[2][j], v);
                    v = __builtin_elementwise_fma(ew,  wc2[3][j], v);
                    v = __builtin_elementwise_fma(pm2, wc2[4][j], v);
                    v = __builtin_elementwise_max(v, zero2);
                    acc2[j] += v;
                }
            }
            float p0=0.f,p1=0.f,p2=0.f;
            #pragma unroll
            for (int j=0;j<4;j++) {
                const float a0v = acc2[j].x*(1.0f/32.0f);
                const float a1v = acc2[j].y*(1.0f/32.0f);
                const int c0 = 2*j, c1 = 2*j+1;
                p0 = fmaf(a0v, sWo[11+d0+c0][0], p0);
                p1 = fmaf(a0v, sWo[11+d0+c0][1], p1);
                p2 = fmaf(a0v, sWo[11+d0+c0][2], p2);
                p0 = fmaf(a1v, sWo[11+d0+c1][0], p0);
                p1 = fmaf(a1v, sWo[11+d0+c1][1], p1);
                p2 = fmaf(a1v, sWo[11+d0+c1][2], p2);
            }
            #pragma unroll
            for (int s=1;s<8;s<<=1) {
                p0 += __shfl_xor(p0,s); p1 += __shfl_xor(p1,s); p2 += __shfl_xor(p2,s);
            }
            if (dsub == 0) {
                const float4 Su = sSu[ng];
                const float vinv = Y1 * __builtin_amdgcn_rcpf(fmaxf(Vn.w,1e-12f));
                const float na0 = 2.f*Y0;
                const float na1 = Su.x*(1.f/32.f) + Vn.x*vinv;
                const float na2 = Su.y*(1.f/32.f) + Vn.y*vinv;
                const float na3 = Su.z*(1.f/32.f) + Vn.z*vinv;
                const float xf[7] = {Pn.x,Pn.y,Pn.z,Vn.x,Vn.y,Vn.z,Vn.w};
                #pragma unroll
                for (int k=0;k<7;k++) {
                    p0 = fmaf(xf[k], sWo[k][0], p0);
                    p1 = fmaf(xf[k], sWo[k][1], p1);
                    p2 = fmaf(xf[k], sWo[k][2], p2);
                }
                p0 += na0*sWo[7][0] + na1*sWo[8][0] + na2*sWo[9][0] + na3*sWo[10][0];
                p1 += na0*sWo[7][1] + na1*sWo[8][1] + na2*sWo[9][1] + na3*sWo[10][1];
                p2 += na0*sWo[7][2] + na1*sWo[8][2] + na2*sWo[9][2] + na3*sWo[10][2];
                float* op = out + ((size_t)b*NN + n)*3;
                op[0] = Pn.x + cmx + p0;
                op[1] = Pn.y + cmy + p1;
                op[2] = Pn.z + cmz + p2;
            }
        }
        __syncthreads();   // full separation: next build's writes vs this main's reads
    }
}

extern "C" void kernel_launch(void* const* d_in, const int* in_sizes, int n_in,
                              void* d_out, int out_size, void* d_ws, size_t ws_size,
                              hipStream_t stream)
{
    const float* in = (const float*)d_in[0];
    const float* Wm = (const float*)d_in[1];
    const float* Wo = (const float*)d_in[2];
    float* out = (float*)d_out;
    float* feats = (float*)d_ws;                               // NB*NN*8 floats
    float* com   = feats + (size_t)NB*NN*8;                    // NB*4 floats
    unsigned char* nbr = (unsigned char*)(com + (size_t)NB*4); // NB*NN*32 u8

    k12_sel<<<NB, 128, 0, stream>>>(in, feats, com, nbr, out);
    k3_main<<<NB, 256, 0, stream>>>(feats, nbr, Wm, Wo, com, out);
}